// Round 34
// baseline (550.372 us; speedup 1.0000x reference)
//

#include <hip/hip_runtime.h>
#include <hip/hip_bf16.h>

#define CIN   1024
#define FEATN 64
#define HH    48
#define WW    160
#define DDN   48
#define EPSV  1e-5f
#define NTAP  27
#define WSLAB 162             // wIdx 0..161 covers w' = -1..160

typedef __attribute__((ext_vector_type(8))) short bf16x8;
typedef __attribute__((ext_vector_type(4))) float f32x4;
typedef __attribute__((ext_vector_type(4))) unsigned short u16x4;

static __device__ __forceinline__ unsigned short f2bf(float x) {
    __hip_bfloat16 h = __float2bfloat16(x);
    return *(unsigned short*)&h;
}

// Direct global->LDS 16B DMA (m104: LDS dest = uniform base + lane*16;
// swizzle via pre-swizzled per-lane GLOBAL source, m173).
static __device__ __forceinline__ void gld16(const void* g, void* l)
{
    __builtin_amdgcn_global_load_lds(
        (const __attribute__((address_space(1))) void*)g,
        (__attribute__((address_space(3))) void*)l,
        16, 0, 0);
}

// ---------------------------------------------------------------------------
__global__ void CostVolume_6201932775918_packw(const float* w3, unsigned short* Wb)
{
    int i = (int)(blockIdx.x * 256 + threadIdx.x);
    if (i >= 64 * NTAP * 128) return;
    int ci  = i & 127;
    int tap = (i >> 7) % NTAP;
    int o   = i / (NTAP * 128);
    Wb[i] = f2bf(w3[o * 3456 + ci * 27 + tap]);
}

__global__ void CostVolume_6201932775918_packw2(const float* w3, unsigned short* Wb2,
                                                unsigned short* Zb)
{
    if (blockIdx.x == 0 && threadIdx.x < 32) Zb[threadIdx.x] = 0;
    int i = (int)(blockIdx.x * 256 + threadIdx.x);
    if (i >= 64 * NTAP * 64) return;
    int ci  = i & 63;
    int tap = (i >> 6) % NTAP;
    int o   = i / (NTAP * 64);
    Wb2[i] = f2bf(w3[o * 1728 + ci * 27 + tap]);
}

// ---------------------------------------------------------------------------
// down_sample: 1x1 conv + BN + ReLU -> bf16 CHANNEL-LAST Lt/Rt [h*W+w][ci]
// ---------------------------------------------------------------------------
__global__ void CostVolume_6201932775918_ds(
    const float* Lf, const float* Rf,
    const float* dsw, const float* dsb,
    const float* g2, const float* b2, const float* m2, const float* v2,
    unsigned short* outL, unsigned short* outR)
{
    const float* in = (blockIdx.y == 0) ? Lf : Rf;
    unsigned short* out = (blockIdx.y == 0) ? outL : outR;
    const int t    = (int)threadIdx.x;
    const int pos0 = (int)blockIdx.x * 64;
    const int oq   = t & 15;            // o = 4*oq + k
    const int pq   = t >> 4;            // pos = pos0 + pq*4 + j

    __shared__ float chunk[64 * 64];

    float acc[4][4];
    #pragma unroll
    for (int k = 0; k < 4; ++k)
        #pragma unroll
        for (int j = 0; j < 4; ++j) acc[k][j] = 0.f;

    for (int cc = 0; cc < 16; ++cc) {
        __syncthreads();
        #pragma unroll
        for (int i = 0; i < 16; ++i) {
            int idx = i * 256 + t;
            int cl = idx >> 6;
            int p  = idx & 63;
            chunk[cl * 64 + p] = in[(cc * 64 + cl) * (HH * WW) + pos0 + p];
        }
        __syncthreads();
        for (int cl = 0; cl < 64; ++cl) {
            int c = cc * 64 + cl;
            float x0 = chunk[cl * 64 + pq * 4 + 0];
            float x1 = chunk[cl * 64 + pq * 4 + 1];
            float x2 = chunk[cl * 64 + pq * 4 + 2];
            float x3 = chunk[cl * 64 + pq * 4 + 3];
            #pragma unroll
            for (int k = 0; k < 4; ++k) {
                float w = dsw[(4 * oq + k) * CIN + c];
                acc[k][0] = fmaf(w, x0, acc[k][0]);
                acc[k][1] = fmaf(w, x1, acc[k][1]);
                acc[k][2] = fmaf(w, x2, acc[k][2]);
                acc[k][3] = fmaf(w, x3, acc[k][3]);
            }
        }
    }

    float s4[4], cb4[4];
    #pragma unroll
    for (int k = 0; k < 4; ++k) {
        int o = 4 * oq + k;
        s4[k]  = g2[o] / sqrtf(v2[o] + EPSV);
        cb4[k] = dsb[o] * s4[k] + b2[o] - m2[o] * s4[k];
    }
    #pragma unroll
    for (int j = 0; j < 4; ++j) {
        u16x4 v;
        #pragma unroll
        for (int k = 0; k < 4; ++k)
            v[k] = f2bf(fmaxf(0.f, fmaf(acc[k][j], s4[k], cb4[k])));
        *(u16x4*)&out[(size_t)(pos0 + pq * 4 + j) * 64 + 4 * oq] = v;
    }
}

// ---------------------------------------------------------------------------
// conv3a: bf16 MFMA implicit GEMM. Waves split M AND N: wave=(mi,ni),
// M=32 (2 m-tiles) x N=80 (5 n-tiles) per wave; each B-frag read feeds 2
// MFMAs => LDS read traffic halved vs r33. DMA staging w/ source swizzle.
// Output: y1t [d][h][w][o] bf16.
// ---------------------------------------------------------------------------
__global__ __launch_bounds__(256) void CostVolume_6201932775918_c3a(
    const unsigned short* Lt, const unsigned short* Rt,
    const unsigned short* Wb, const unsigned short* Zb,
    const float* cb3, const float* g3, const float* b3,
    const float* m3, const float* v3,
    unsigned short* y1t)
{
    const int h    = (int)blockIdx.x;
    const int d    = (int)blockIdx.y;
    const int t    = (int)threadIdx.x;
    const int wave = t >> 6;
    const int lane = t & 63;
    const int l15  = lane & 15;
    const int lhi  = lane >> 4;
    const int mi   = wave >> 1;         // 0..1 (M half)
    const int ni   = wave & 1;          // 0..1 (N half)

    __shared__ __align__(16) unsigned short slab[WSLAB * 128];   // 41472 B

    f32x4 acc[2][5];
    #pragma unroll
    for (int m = 0; m < 2; ++m)
        #pragma unroll
        for (int n = 0; n < 5; ++n) acc[m][n] = (f32x4){0.f, 0.f, 0.f, 0.f};

    char* slabB = (char*)slab;

    for (int kd = 0; kd < 3; ++kd) {
        const int dp = d + kd - 1;
        if (dp < 0 || dp >= DDN) continue;
        for (int kh = 0; kh < 3; ++kh) {
            const int hp = h + kh - 1;
            if (hp < 0 || hp >= HH) continue;
            __syncthreads();
            const unsigned short* Lrow = Lt + (size_t)hp * WW * 64;
            const unsigned short* Rrow = Rt + ((size_t)hp * WW - (size_t)dp) * 64;
            #pragma unroll
            for (int i = 0; i < 11; ++i) {
                int witer = i * 4 + wave;
                int e = witer * 64 + lane;
                if (e < WSLAB * 16) {
                    int wIdx = e >> 4;
                    int c16  = (e & 15) ^ (wIdx & 15);   // source-side inverse swizzle
                    int wp   = wIdx - 1;
                    const unsigned short* src = Zb;
                    if (wp >= dp && wp < WW)
                        src = (c16 < 8) ? (Lrow + (size_t)wp * 64 + c16 * 8)
                                        : (Rrow + (size_t)wp * 64 + (c16 - 8) * 8);
                    gld16(src, slabB + (size_t)witer * 1024);
                }
            }
            __syncthreads();
            const int tapbase = (kd * 3 + kh) * 3;
            #pragma unroll
            for (int kw = 0; kw < 3; ++kw) {
                const unsigned short* w0row =
                    Wb + (32 * mi + l15) * (NTAP * 128) + (tapbase + kw) * 128 + lhi * 8;
                const unsigned short* w1row = w0row + 16 * (NTAP * 128);
                #pragma unroll
                for (int kc = 0; kc < 4; ++kc) {
                    bf16x8 a0 = *(const bf16x8*)(w0row + kc * 32);
                    bf16x8 a1 = *(const bf16x8*)(w1row + kc * 32);
                    const int ci0x2 = (kc * 32 + lhi * 8) * 2;
                    #pragma unroll
                    for (int n = 0; n < 5; ++n) {
                        int wIdx = 16 * (5 * ni + n) + l15 + kw;
                        int byte = (wIdx * 256 + ci0x2) ^ ((wIdx & 15) << 4);
                        bf16x8 bfrag = *(const bf16x8*)(slabB + byte);
                        acc[0][n] = __builtin_amdgcn_mfma_f32_16x16x32_bf16(
                            a0, bfrag, acc[0][n], 0, 0, 0);
                        acc[1][n] = __builtin_amdgcn_mfma_f32_16x16x32_bf16(
                            a1, bfrag, acc[1][n], 0, 0, 0);
                    }
                }
            }
        }
    }

    #pragma unroll
    for (int m = 0; m < 2; ++m) {
        float s4[4], cb4[4];
        #pragma unroll
        for (int r = 0; r < 4; ++r) {
            const int o = 32 * mi + 16 * m + lhi * 4 + r;
            s4[r]  = g3[o] / sqrtf(v3[o] + EPSV);
            cb4[r] = cb3[o] * s4[r] + b3[o] - m3[o] * s4[r];
        }
        unsigned short* ybase =
            y1t + ((size_t)(d * HH + h) * WW) * 64 + 32 * mi + 16 * m + lhi * 4;
        #pragma unroll
        for (int n = 0; n < 5; ++n) {
            int w = 16 * (5 * ni + n) + l15;
            u16x4 v;
            #pragma unroll
            for (int r = 0; r < 4; ++r)
                v[r] = f2bf(fmaxf(0.f, fmaf(acc[m][n][r], s4[r], cb4[r])));
            *(u16x4*)(ybase + (size_t)w * 64) = v;
        }
    }
}

// ---------------------------------------------------------------------------
// conv3b: same M/N wave split + dbuf + issue-ahead DMA pipeline.
// K = 64 ci x 27 taps. Output f32 ((o*D+d)*H+h)*W + w.
// ---------------------------------------------------------------------------
__global__ __launch_bounds__(256) void CostVolume_6201932775918_c3b(
    const unsigned short* y1t, const unsigned short* Wb2,
    const unsigned short* Zb,
    const float* cb3, const float* g3, const float* b3,
    const float* m3, const float* v3,
    float* outp)
{
    const int h    = (int)blockIdx.x;
    const int d    = (int)blockIdx.y;
    const int t    = (int)threadIdx.x;
    const int wave = t >> 6;
    const int lane = t & 63;
    const int l15  = lane & 15;
    const int lhi  = lane >> 4;
    const int mi   = wave >> 1;
    const int ni   = wave & 1;

    __shared__ __align__(16) unsigned short S[2][WSLAB * 64];    // 41472 B

    f32x4 acc[2][5];
    #pragma unroll
    for (int m = 0; m < 2; ++m)
        #pragma unroll
        for (int n = 0; n < 5; ++n) acc[m][n] = (f32x4){0.f, 0.f, 0.f, 0.f};

    const int kd0 = (d == 0) ? 1 : 0;
    const int kd1 = (d == DDN - 1) ? 1 : 2;
    const int kh0 = (h == 0) ? 1 : 0;
    const int kh1 = (h == HH - 1) ? 1 : 2;
    const int nh  = kh1 - kh0 + 1;
    const int P   = (kd1 - kd0 + 1) * nh;

    auto stage_b = [&](int p, int buf) {
        int kd = kd0 + p / nh;
        int kh = kh0 + p % nh;
        int dp = d + kd - 1, hp = h + kh - 1;
        const unsigned short* yrow = y1t + ((size_t)(dp * HH + hp) * WW) * 64;
        char* SB = (char*)S[buf];
        #pragma unroll
        for (int i = 0; i < 6; ++i) {
            int witer = i * 4 + wave;
            int e = witer * 64 + lane;
            if (e < WSLAB * 8) {
                int wIdx = e >> 3;
                int c8   = (e & 7) ^ (wIdx & 7);    // source-side inverse swizzle
                int wp   = wIdx - 1;
                const unsigned short* src = Zb;
                if (wp >= 0 && wp < WW)
                    src = yrow + (size_t)wp * 64 + c8 * 8;
                gld16(src, SB + (size_t)witer * 1024);
            }
        }
    };

    stage_b(0, 0);
    int buf = 0;
    for (int p = 0; p < P; ++p) {
        __syncthreads();                 // drains stage(p); syncs waves
        if (p + 1 < P) stage_b(p + 1, buf ^ 1);   // flies under MFMAs below
        int kd = kd0 + p / nh;
        int kh = kh0 + p % nh;
        const int tap0 = (kd * 3 + kh) * 3;
        char* SB = (char*)S[buf];
        #pragma unroll
        for (int kw = 0; kw < 3; ++kw) {
            const unsigned short* w0row =
                Wb2 + (32 * mi + l15) * (NTAP * 64) + (tap0 + kw) * 64 + lhi * 8;
            const unsigned short* w1row = w0row + 16 * (NTAP * 64);
            #pragma unroll
            for (int kc = 0; kc < 2; ++kc) {
                bf16x8 a0 = *(const bf16x8*)(w0row + kc * 32);
                bf16x8 a1 = *(const bf16x8*)(w1row + kc * 32);
                const int ci2 = (kc * 32 + lhi * 8) * 2;
                #pragma unroll
                for (int n = 0; n < 5; ++n) {
                    int wIdx = 16 * (5 * ni + n) + l15 + kw;
                    int byte = (wIdx * 128 + ci2) ^ ((wIdx & 7) << 4);
                    bf16x8 b = *(const bf16x8*)(SB + byte);
                    acc[0][n] = __builtin_amdgcn_mfma_f32_16x16x32_bf16(
                        a0, b, acc[0][n], 0, 0, 0);
                    acc[1][n] = __builtin_amdgcn_mfma_f32_16x16x32_bf16(
                        a1, b, acc[1][n], 0, 0, 0);
                }
            }
        }
        buf ^= 1;
    }

    #pragma unroll
    for (int m = 0; m < 2; ++m) {
        float s4[4], cb4[4];
        #pragma unroll
        for (int r = 0; r < 4; ++r) {
            const int o = 32 * mi + 16 * m + lhi * 4 + r;
            s4[r]  = g3[o] / sqrtf(v3[o] + EPSV);
            cb4[r] = cb3[o] * s4[r] + b3[o] - m3[o] * s4[r];
        }
        #pragma unroll
        for (int r = 0; r < 4; ++r) {
            const int o = 32 * mi + 16 * m + lhi * 4 + r;
            float* orow = outp + ((size_t)(o * DDN + d) * HH + h) * WW;
            #pragma unroll
            for (int n = 0; n < 5; ++n) {
                int w = 16 * (5 * ni + n) + l15;
                orow[w] = fmaxf(0.f, fmaf(acc[m][n][r], s4[r], cb4[r]));
            }
        }
    }
}

// ---------------------------------------------------------------------------
extern "C" void kernel_launch(void* const* d_in, const int* in_sizes, int n_in,
                              void* d_out, int out_size, void* d_ws, size_t ws_size,
                              hipStream_t stream)
{
    (void)in_sizes; (void)n_in; (void)out_size;

    const float* Lf  = (const float*)d_in[0];
    const float* Rf  = (const float*)d_in[1];
    const float* dsw = (const float*)d_in[2];
    const float* dsb = (const float*)d_in[3];
    const float* g2  = (const float*)d_in[4];
    const float* b2  = (const float*)d_in[5];
    const float* m2  = (const float*)d_in[6];
    const float* v2  = (const float*)d_in[7];
    const float* w3a = (const float*)d_in[8];
    const float* cba = (const float*)d_in[9];
    const float* g3a = (const float*)d_in[10];
    const float* b3a = (const float*)d_in[11];
    const float* m3a = (const float*)d_in[12];
    const float* v3a = (const float*)d_in[13];
    const float* w3b = (const float*)d_in[14];
    const float* cbb = (const float*)d_in[15];
    const float* g3b = (const float*)d_in[16];
    const float* b3b = (const float*)d_in[17];
    const float* m3b = (const float*)d_in[18];
    const float* v3b = (const float*)d_in[19];

    float* outF = (float*)d_out;       // output dtype: FLOAT32

    unsigned short* Lt  = (unsigned short*)d_ws;
    unsigned short* Rt  = (unsigned short*)((char*)d_ws + 983040);
    unsigned short* Wb  = (unsigned short*)((char*)d_ws + 1966080);
    unsigned short* Wb2 = (unsigned short*)((char*)d_ws + 2408448);
    unsigned short* y1t = (unsigned short*)((char*)d_ws + 2629632);
    unsigned short* Zb  = (unsigned short*)((char*)d_ws + 49815552);
    if (ws_size < 49815552 + 64) return;

    CostVolume_6201932775918_packw<<<dim3(864), 256, 0, stream>>>(w3a, Wb);
    CostVolume_6201932775918_packw2<<<dim3(432), 256, 0, stream>>>(w3b, Wb2, Zb);

    CostVolume_6201932775918_ds<<<dim3(120, 2), 256, 0, stream>>>(
        Lf, Rf, dsw, dsb, g2, b2, m2, v2, Lt, Rt);

    CostVolume_6201932775918_c3a<<<dim3(48, 48), 256, 0, stream>>>(
        Lt, Rt, Wb, Zb, cba, g3a, b3a, m3a, v3a, y1t);

    CostVolume_6201932775918_c3b<<<dim3(48, 48), 256, 0, stream>>>(
        y1t, Wb2, Zb, cbb, g3b, b3b, m3b, v3b, outF);
}

// Round 35
// 434.124 us; speedup vs baseline: 1.2678x; 1.2678x over previous
//

#include <hip/hip_runtime.h>
#include <hip/hip_bf16.h>

#define CIN   1024
#define FEATN 64
#define HH    48
#define WW    160
#define DDN   48
#define EPSV  1e-5f
#define NTAP  27
#define WSLAB 162             // wIdx 0..161 covers w' = -1..160

typedef __attribute__((ext_vector_type(8))) short bf16x8;
typedef __attribute__((ext_vector_type(4))) float f32x4;
typedef __attribute__((ext_vector_type(4))) unsigned short u16x4;

static __device__ __forceinline__ unsigned short f2bf(float x) {
    __hip_bfloat16 h = __float2bfloat16(x);
    return *(unsigned short*)&h;
}

// Direct global->LDS 16B DMA. LDS dest = wave-uniform base + lane*16 (m104);
// swizzle achieved by pre-swizzling the per-lane GLOBAL source (m173).
static __device__ __forceinline__ void gld16(const void* g, void* l)
{
    __builtin_amdgcn_global_load_lds(
        (const __attribute__((address_space(1))) void*)g,
        (__attribute__((address_space(3))) void*)l,
        16, 0, 0);
}

// ---------------------------------------------------------------------------
// Pack conv3a weights: Wb[o][tap][ci128] bf16 from w3a[o][ci][tap] f32
// ---------------------------------------------------------------------------
__global__ void CostVolume_6201932775918_packw(const float* w3, unsigned short* Wb)
{
    int i = (int)(blockIdx.x * 256 + threadIdx.x);
    if (i >= 64 * NTAP * 128) return;
    int ci  = i & 127;
    int tap = (i >> 7) % NTAP;
    int o   = i / (NTAP * 128);
    Wb[i] = f2bf(w3[o * 3456 + ci * 27 + tap]);
}

// ---------------------------------------------------------------------------
// Pack conv3b weights + zero the 16B zeros block (used by masked DMA lanes).
// ---------------------------------------------------------------------------
__global__ void CostVolume_6201932775918_packw2(const float* w3, unsigned short* Wb2,
                                                unsigned short* Zb)
{
    if (blockIdx.x == 0 && threadIdx.x < 32) Zb[threadIdx.x] = 0;
    int i = (int)(blockIdx.x * 256 + threadIdx.x);
    if (i >= 64 * NTAP * 64) return;
    int ci  = i & 63;
    int tap = (i >> 6) % NTAP;
    int o   = i / (NTAP * 64);
    Wb2[i] = f2bf(w3[o * 1728 + ci * 27 + tap]);
}

// ---------------------------------------------------------------------------
// down_sample: 1x1 conv + BN + ReLU -> bf16 CHANNEL-LAST Lt/Rt [h*W+w][ci]
// ---------------------------------------------------------------------------
__global__ void CostVolume_6201932775918_ds(
    const float* Lf, const float* Rf,
    const float* dsw, const float* dsb,
    const float* g2, const float* b2, const float* m2, const float* v2,
    unsigned short* outL, unsigned short* outR)
{
    const float* in = (blockIdx.y == 0) ? Lf : Rf;
    unsigned short* out = (blockIdx.y == 0) ? outL : outR;
    const int t    = (int)threadIdx.x;
    const int pos0 = (int)blockIdx.x * 64;
    const int oq   = t & 15;            // o = 4*oq + k
    const int pq   = t >> 4;            // pos = pos0 + pq*4 + j

    __shared__ float chunk[64 * 64];

    float acc[4][4];
    #pragma unroll
    for (int k = 0; k < 4; ++k)
        #pragma unroll
        for (int j = 0; j < 4; ++j) acc[k][j] = 0.f;

    for (int cc = 0; cc < 16; ++cc) {
        __syncthreads();
        #pragma unroll
        for (int i = 0; i < 16; ++i) {
            int idx = i * 256 + t;
            int cl = idx >> 6;
            int p  = idx & 63;
            chunk[cl * 64 + p] = in[(cc * 64 + cl) * (HH * WW) + pos0 + p];
        }
        __syncthreads();
        for (int cl = 0; cl < 64; ++cl) {
            int c = cc * 64 + cl;
            float x0 = chunk[cl * 64 + pq * 4 + 0];
            float x1 = chunk[cl * 64 + pq * 4 + 1];
            float x2 = chunk[cl * 64 + pq * 4 + 2];
            float x3 = chunk[cl * 64 + pq * 4 + 3];
            #pragma unroll
            for (int k = 0; k < 4; ++k) {
                float w = dsw[(4 * oq + k) * CIN + c];
                acc[k][0] = fmaf(w, x0, acc[k][0]);
                acc[k][1] = fmaf(w, x1, acc[k][1]);
                acc[k][2] = fmaf(w, x2, acc[k][2]);
                acc[k][3] = fmaf(w, x3, acc[k][3]);
            }
        }
    }

    float s4[4], cb4[4];
    #pragma unroll
    for (int k = 0; k < 4; ++k) {
        int o = 4 * oq + k;
        s4[k]  = g2[o] / sqrtf(v2[o] + EPSV);
        cb4[k] = dsb[o] * s4[k] + b2[o] - m2[o] * s4[k];
    }
    #pragma unroll
    for (int j = 0; j < 4; ++j) {
        u16x4 v;
        #pragma unroll
        for (int k = 0; k < 4; ++k)
            v[k] = f2bf(fmaxf(0.f, fmaf(acc[k][j], s4[k], cb4[k])));
        *(u16x4*)&out[(size_t)(pos0 + pq * 4 + j) * 64 + 4 * oq] = v;
    }
}

// ---------------------------------------------------------------------------
// conv3a: bf16 MFMA implicit GEMM; staging via global_load_lds 16B DMA with
// source-side swizzle inversion; masked lanes read the zeros block.
// (r33 structure verbatim — best measured: 223 us, MfmaUtil 30.6%)
// ---------------------------------------------------------------------------
__global__ __launch_bounds__(256) void CostVolume_6201932775918_c3a(
    const unsigned short* Lt, const unsigned short* Rt,
    const unsigned short* Wb, const unsigned short* Zb,
    const float* cb3, const float* g3, const float* b3,
    const float* m3, const float* v3,
    unsigned short* y1t)
{
    const int h    = (int)blockIdx.x;
    const int d    = (int)blockIdx.y;
    const int t    = (int)threadIdx.x;
    const int wave = t >> 6;
    const int lane = t & 63;
    const int l15  = lane & 15;
    const int lhi  = lane >> 4;

    __shared__ __align__(16) unsigned short slab[WSLAB * 128];   // 41472 B

    f32x4 acc[10];
    #pragma unroll
    for (int n = 0; n < 10; ++n) acc[n] = (f32x4){0.f, 0.f, 0.f, 0.f};

    char* slabB = (char*)slab;

    for (int kd = 0; kd < 3; ++kd) {
        const int dp = d + kd - 1;
        if (dp < 0 || dp >= DDN) continue;
        for (int kh = 0; kh < 3; ++kh) {
            const int hp = h + kh - 1;
            if (hp < 0 || hp >= HH) continue;
            __syncthreads();                 // prior reads of slab complete
            // ---- stage via DMA: chunk e = witer*64 + lane, 16B each ----
            const unsigned short* Lrow = Lt + (size_t)hp * WW * 64;
            const unsigned short* Rrow = Rt + ((size_t)hp * WW - (size_t)dp) * 64;
            #pragma unroll
            for (int i = 0; i < 11; ++i) {
                int witer = i * 4 + wave;
                int e = witer * 64 + lane;
                if (e < WSLAB * 16) {
                    int wIdx = e >> 4;
                    int c16  = (e & 15) ^ (wIdx & 15);   // source-side inverse swizzle
                    int wp   = wIdx - 1;
                    const unsigned short* src = Zb;
                    if (wp >= dp && wp < WW)
                        src = (c16 < 8) ? (Lrow + (size_t)wp * 64 + c16 * 8)
                                        : (Rrow + (size_t)wp * 64 + (c16 - 8) * 8);
                    gld16(src, slabB + (size_t)witer * 1024);
                }
            }
            __syncthreads();                 // drains DMA (vmcnt) + sync
            // ---- MFMA: 3 kw x 4 ci-chunks x 10 n-tiles ----
            const int tapbase = (kd * 3 + kh) * 3;
            #pragma unroll
            for (int kw = 0; kw < 3; ++kw) {
                const unsigned short* wrow =
                    Wb + (16 * wave + l15) * (NTAP * 128) + (tapbase + kw) * 128 + lhi * 8;
                #pragma unroll
                for (int kc = 0; kc < 4; ++kc) {
                    bf16x8 afrag = *(const bf16x8*)(wrow + kc * 32);
                    const int ci0x2 = (kc * 32 + lhi * 8) * 2;
                    #pragma unroll
                    for (int n = 0; n < 10; ++n) {
                        int wIdx = 16 * n + l15 + kw;
                        int byte = (wIdx * 256 + ci0x2) ^ ((wIdx & 15) << 4);
                        bf16x8 bfrag = *(const bf16x8*)(slabB + byte);
                        acc[n] = __builtin_amdgcn_mfma_f32_16x16x32_bf16(
                            afrag, bfrag, acc[n], 0, 0, 0);
                    }
                }
            }
        }
    }

    float s4[4], cb4[4];
    #pragma unroll
    for (int r = 0; r < 4; ++r) {
        const int o = 16 * wave + lhi * 4 + r;
        s4[r]  = g3[o] / sqrtf(v3[o] + EPSV);
        cb4[r] = cb3[o] * s4[r] + b3[o] - m3[o] * s4[r];
    }
    unsigned short* ybase =
        y1t + ((size_t)(d * HH + h) * WW) * 64 + 16 * wave + lhi * 4;
    #pragma unroll
    for (int n = 0; n < 10; ++n) {
        int w = 16 * n + l15;
        u16x4 v;
        #pragma unroll
        for (int r = 0; r < 4; ++r)
            v[r] = f2bf(fmaxf(0.f, fmaf(acc[n][r], s4[r], cb4[r])));
        *(u16x4*)(ybase + (size_t)w * 64) = v;
    }
}

// ---------------------------------------------------------------------------
// conv3b: dbuf + ISSUE-AHEAD pipeline: stage(p+1) DMA issued right after the
// barrier, flying under phase p's MFMAs. (r33 structure verbatim)
// ---------------------------------------------------------------------------
__global__ __launch_bounds__(256) void CostVolume_6201932775918_c3b(
    const unsigned short* y1t, const unsigned short* Wb2,
    const unsigned short* Zb,
    const float* cb3, const float* g3, const float* b3,
    const float* m3, const float* v3,
    float* outp)
{
    const int h    = (int)blockIdx.x;
    const int d    = (int)blockIdx.y;
    const int t    = (int)threadIdx.x;
    const int wave = t >> 6;
    const int lane = t & 63;
    const int l15  = lane & 15;
    const int lhi  = lane >> 4;

    __shared__ __align__(16) unsigned short S[2][WSLAB * 64];    // 41472 B

    f32x4 acc[10];
    #pragma unroll
    for (int n = 0; n < 10; ++n) acc[n] = (f32x4){0.f, 0.f, 0.f, 0.f};

    const int kd0 = (d == 0) ? 1 : 0;
    const int kd1 = (d == DDN - 1) ? 1 : 2;
    const int kh0 = (h == 0) ? 1 : 0;
    const int kh1 = (h == HH - 1) ? 1 : 2;
    const int nh  = kh1 - kh0 + 1;
    const int P   = (kd1 - kd0 + 1) * nh;

    auto stage_b = [&](int p, int buf) {
        int kd = kd0 + p / nh;
        int kh = kh0 + p % nh;
        int dp = d + kd - 1, hp = h + kh - 1;
        const unsigned short* yrow = y1t + ((size_t)(dp * HH + hp) * WW) * 64;
        char* SB = (char*)S[buf];
        #pragma unroll
        for (int i = 0; i < 6; ++i) {
            int witer = i * 4 + wave;
            int e = witer * 64 + lane;
            if (e < WSLAB * 8) {
                int wIdx = e >> 3;
                int c8   = (e & 7) ^ (wIdx & 7);    // source-side inverse swizzle
                int wp   = wIdx - 1;
                const unsigned short* src = Zb;
                if (wp >= 0 && wp < WW)
                    src = yrow + (size_t)wp * 64 + c8 * 8;
                gld16(src, SB + (size_t)witer * 1024);
            }
        }
    };

    stage_b(0, 0);
    int buf = 0;
    for (int p = 0; p < P; ++p) {
        __syncthreads();                 // drains stage(p); syncs waves
        if (p + 1 < P) stage_b(p + 1, buf ^ 1);   // flies under MFMAs below
        int kd = kd0 + p / nh;
        int kh = kh0 + p % nh;
        const int tap0 = (kd * 3 + kh) * 3;
        char* SB = (char*)S[buf];
        #pragma unroll
        for (int kw = 0; kw < 3; ++kw) {
            const unsigned short* wrow =
                Wb2 + (16 * wave + l15) * (NTAP * 64) + (tap0 + kw) * 64 + lhi * 8;
            #pragma unroll
            for (int kc = 0; kc < 2; ++kc) {
                bf16x8 afrag = *(const bf16x8*)(wrow + kc * 32);
                const int ci2 = (kc * 32 + lhi * 8) * 2;
                #pragma unroll
                for (int n = 0; n < 10; ++n) {
                    int wIdx = 16 * n + l15 + kw;
                    int byte = (wIdx * 128 + ci2) ^ ((wIdx & 7) << 4);
                    bf16x8 b = *(const bf16x8*)(SB + byte);
                    acc[n] = __builtin_amdgcn_mfma_f32_16x16x32_bf16(
                        afrag, b, acc[n], 0, 0, 0);
                }
            }
        }
        buf ^= 1;
    }

    float s4[4], cb4[4];
    #pragma unroll
    for (int r = 0; r < 4; ++r) {
        const int o = 16 * wave + lhi * 4 + r;
        s4[r]  = g3[o] / sqrtf(v3[o] + EPSV);
        cb4[r] = cb3[o] * s4[r] + b3[o] - m3[o] * s4[r];
    }
    #pragma unroll
    for (int r = 0; r < 4; ++r) {
        const int o = 16 * wave + lhi * 4 + r;
        float* orow = outp + ((size_t)(o * DDN + d) * HH + h) * WW;
        #pragma unroll
        for (int n = 0; n < 10; ++n) {
            int w = 16 * n + l15;
            orow[w] = fmaxf(0.f, fmaf(acc[n][r], s4[r], cb4[r]));
        }
    }
}

// ---------------------------------------------------------------------------
extern "C" void kernel_launch(void* const* d_in, const int* in_sizes, int n_in,
                              void* d_out, int out_size, void* d_ws, size_t ws_size,
                              hipStream_t stream)
{
    (void)in_sizes; (void)n_in; (void)out_size;

    const float* Lf  = (const float*)d_in[0];
    const float* Rf  = (const float*)d_in[1];
    const float* dsw = (const float*)d_in[2];
    const float* dsb = (const float*)d_in[3];
    const float* g2  = (const float*)d_in[4];
    const float* b2  = (const float*)d_in[5];
    const float* m2  = (const float*)d_in[6];
    const float* v2  = (const float*)d_in[7];
    const float* w3a = (const float*)d_in[8];
    const float* cba = (const float*)d_in[9];
    const float* g3a = (const float*)d_in[10];
    const float* b3a = (const float*)d_in[11];
    const float* m3a = (const float*)d_in[12];
    const float* v3a = (const float*)d_in[13];
    const float* w3b = (const float*)d_in[14];
    const float* cbb = (const float*)d_in[15];
    const float* g3b = (const float*)d_in[16];
    const float* b3b = (const float*)d_in[17];
    const float* m3b = (const float*)d_in[18];
    const float* v3b = (const float*)d_in[19];

    float* outF = (float*)d_out;       // output dtype: FLOAT32

    // ws layout (bytes): Lt@0, Rt@983040, Wb@1966080, Wb2@2408448,
    // y1t@2629632 (47,185,920), Zb@49,815,552 (64B zeros)
    unsigned short* Lt  = (unsigned short*)d_ws;
    unsigned short* Rt  = (unsigned short*)((char*)d_ws + 983040);
    unsigned short* Wb  = (unsigned short*)((char*)d_ws + 1966080);
    unsigned short* Wb2 = (unsigned short*)((char*)d_ws + 2408448);
    unsigned short* y1t = (unsigned short*)((char*)d_ws + 2629632);
    unsigned short* Zb  = (unsigned short*)((char*)d_ws + 49815552);
    if (ws_size < 49815552 + 64) return;

    CostVolume_6201932775918_packw<<<dim3(864), 256, 0, stream>>>(w3a, Wb);
    CostVolume_6201932775918_packw2<<<dim3(432), 256, 0, stream>>>(w3b, Wb2, Zb);

    CostVolume_6201932775918_ds<<<dim3(120, 2), 256, 0, stream>>>(
        Lf, Rf, dsw, dsb, g2, b2, m2, v2, Lt, Rt);

    CostVolume_6201932775918_c3a<<<dim3(48, 48), 256, 0, stream>>>(
        Lt, Rt, Wb, Zb, cba, g3a, b3a, m3a, v3a, y1t);

    CostVolume_6201932775918_c3b<<<dim3(48, 48), 256, 0, stream>>>(
        y1t, Wb2, Zb, cbb, g3b, b3b, m3b, v3b, outF);
}